// Round 7
// baseline (158.995 us; speedup 1.0000x reference)
//
#include <hip/hip_runtime.h>
#include <cstdint>
#include <cstddef>

// Problem constants
#define B_  16
#define C_  384
#define H_  48
#define W_  48
#define HW_ 2304        // 48*48

typedef __bf16 bf16x8 __attribute__((ext_vector_type(8)));
typedef float  f32x4  __attribute__((ext_vector_type(4)));
typedef unsigned short u16x8 __attribute__((ext_vector_type(8)));

typedef __attribute__((address_space(3))) void       lds_void;
typedef const __attribute__((address_space(1))) void gbl_void;

__device__ __forceinline__ unsigned short f2bf(float f) {
    union { float f; unsigned int u; } v; v.f = f;
    unsigned int r = v.u + 0x7fffu + ((v.u >> 16) & 1u);   // RNE
    return (unsigned short)(r >> 16);
}
__device__ __forceinline__ float bf2f(unsigned short u) {
    union { unsigned int u; float f; } v; v.u = ((unsigned int)u) << 16;
    return v.f;
}

// ---------------------------------------------------------------------------
// cast both weight matrices fp32 -> bf16 in one launch.
// ---------------------------------------------------------------------------
__global__ void castw2_kernel(const float* __restrict__ wv, unsigned short* __restrict__ dv,
                              const float* __restrict__ wp, unsigned short* __restrict__ dp) {
    const int blk = blockIdx.x;
    const float* s = (blk < 144) ? wv : wp;
    unsigned short* d = (blk < 144) ? dv : dp;
    const int i = ((blk < 144 ? blk : blk - 144) * 256 + threadIdx.x) * 4;
    const float4 v = *(const float4*)&s[i];
    ushort4 o; o.x = f2bf(v.x); o.y = f2bf(v.y); o.z = f2bf(v.z); o.w = f2bf(v.w);
    *(ushort4*)&d[i] = o;
}

// ---------------------------------------------------------------------------
// transpose-cast + fused 3x3 adaptive pool.
// x[b][c][p] fp32 -> xT[b][p][c] bf16; px[b][c][r] += block partial sums/256.
// Each thread's float4 chunk (4 consecutive p, 4-aligned, 48|64 geometry) lies
// in exactly one h row and one pool region.  px must be zeroed before launch.
// grid (36, 6, 16), block 256.
// ---------------------------------------------------------------------------
__global__ __launch_bounds__(256) void tcast_pool_kernel(const float* __restrict__ x,
                                                         unsigned short* __restrict__ xT,
                                                         float* __restrict__ px) {
    __shared__ unsigned short tile[64][68];
    __shared__ float pp[6][64];              // [hbit*3 + rj][c-local]
    const int t  = threadIdx.x;
    const int b  = blockIdx.z;
    const int p0 = blockIdx.x * 64, c0 = blockIdx.y * 64;
    const float* xb = x + ((size_t)b * C_ + c0) * HW_ + p0;

    for (int i = t; i < 384; i += 256) (&pp[0][0])[i] = 0.f;

    float4 vv[4];
#pragma unroll
    for (int pass = 0; pass < 4; ++pass) {
        const int cr = pass * 16 + (t >> 4);
        const int pc = (t & 15) * 4;
        vv[pass] = *(const float4*)&xb[(size_t)cr * HW_ + pc];
        tile[pc + 0][cr] = f2bf(vv[pass].x); tile[pc + 1][cr] = f2bf(vv[pass].y);
        tile[pc + 2][cr] = f2bf(vv[pass].z); tile[pc + 3][cr] = f2bf(vv[pass].w);
    }
    __syncthreads();   // tile ready AND pp zeroed

    unsigned short* xTb = xT + ((size_t)b * HW_ + p0) * C_ + c0;
#pragma unroll
    for (int pass = 0; pass < 4; ++pass) {
        const int pr = pass * 16 + (t >> 4);
        const int cc = (t & 15) * 4;
        *(ushort4*)&xTb[(size_t)pr * C_ + cc] = *(const ushort4*)&tile[pr][cc];
    }

    // pool accumulation (fp32 source)
    const int h0 = p0 / W_;
    const int p  = p0 + (t & 15) * 4;
    const int hb = p / W_ - h0;              // 0 or 1, same for all 4 elems
    const int rj = (p % W_) >> 4;            // same for all 4 elems
#pragma unroll
    for (int pass = 0; pass < 4; ++pass) {
        const int cl = pass * 16 + (t >> 4);
        const float s = vv[pass].x + vv[pass].y + vv[pass].z + vv[pass].w;
        atomicAdd(&pp[hb * 3 + rj][cl], s);
    }
    __syncthreads();

    for (int i = t; i < 384; i += 256) {
        const int cl = i & 63;
        const int slot = i >> 6;             // 0..5
        const int h = h0 + (slot / 3);
        const int r = (h >> 4) * 3 + (slot % 3);
        atomicAdd(&px[((size_t)b * C_ + c0 + cl) * 9 + r],
                  pp[slot][cl] * (1.f / 256.f));
    }
}

// ---------------------------------------------------------------------------
// small projections -> kernT[b][q][c] bf16.  emb derived from px.
// ---------------------------------------------------------------------------
__global__ void small_kernel(const float* __restrict__ px,
                             const float* __restrict__ Wq, const float* __restrict__ bq,
                             const float* __restrict__ Wk, const float* __restrict__ bk,
                             const float* __restrict__ Wg, const float* __restrict__ bg,
                             unsigned short* __restrict__ kernT) {
    const int b = blockIdx.y;
    const int o = blockIdx.x * 128 + threadIdx.x;

    __shared__ float px_l[C_ * 9];
    __shared__ float emb_l[C_];
    __shared__ float wg_l[81];
    __shared__ float bg_l[9];

    for (int idx = threadIdx.x; idx < C_ * 9; idx += 128) px_l[idx] = px[(size_t)b * C_ * 9 + idx];
    if (threadIdx.x < 81) wg_l[threadIdx.x] = Wg[threadIdx.x];
    if (threadIdx.x < 9)  bg_l[threadIdx.x] = bg[threadIdx.x];
    __syncthreads();
    for (int idx = threadIdx.x; idx < C_; idx += 128) {
        float s0 = 0.f;
#pragma unroll
        for (int p = 0; p < 9; ++p) s0 += px_l[idx * 9 + p];
        emb_l[idx] = s0 * (1.f / 9.f);
    }
    __syncthreads();

    float accq[9];
#pragma unroll
    for (int p = 0; p < 9; ++p) accq[p] = bq[o];
    float acck = bk[o];
    const float* wq_row = Wq + (size_t)o * C_;
    const float* wk_row = Wk + (size_t)o * C_;
    for (int i = 0; i < C_; ++i) {
        const float w = wq_row[i];
#pragma unroll
        for (int p = 0; p < 9; ++p) accq[p] = fmaf(w, px_l[i * 9 + p], accq[p]);
        acck = fmaf(wk_row[i], emb_l[i], acck);
    }

    float kf[9], mean = 0.f;
#pragma unroll
    for (int q = 0; q < 9; ++q) {
        float a = bg_l[q];
#pragma unroll
        for (int p = 0; p < 9; ++p) a = fmaf(accq[p], wg_l[q * 9 + p], a);
        kf[q] = a; mean += a;
    }
    mean *= (1.f / 9.f);
    const float sig = 1.f / (1.f + expf(-acck));
#pragma unroll
    for (int q = 0; q < 9; ++q)
        kernT[((size_t)b * 9 + q) * C_ + o] = f2bf(kf[q] - sig * mean);
}

// ---------------------------------------------------------------------------
// bf16 MFMA GEMM, BK=64, XOR-swizzled LDS (pre-swizzled global source,
// linear global_load_lds dest, swizzled ds_read), XCD-chunked 1-D grid.
// R4-proven structure: 1-phase, 2 barriers per K-step, 6 K-steps.
// ---------------------------------------------------------------------------
template<int BIAS_COL, bool OUT_BF16, int BMAJOR>
__global__ __launch_bounds__(256) void gemm_bt(const unsigned short* __restrict__ A,
                                               const unsigned short* __restrict__ Bt,
                                               const float* __restrict__ bias,
                                               void* __restrict__ Yv,
                                               int N, int nMt, int nNt, int perB,
                                               long long sA, long long sB, long long sY) {
    const int q8  = gridDim.x >> 3;
    const int swz = (blockIdx.x & 7) * q8 + (blockIdx.x >> 3);
    const int b   = swz / perB;
    const int r   = swz % perB;
    const int mtile = BMAJOR ? (r % nMt) : (r / nNt);
    const int ntile = BMAJOR ? (r / nMt) : (r % nNt);
    const int m0 = mtile * 128, n0 = ntile * 128;

    const int t = threadIdx.x;
    const int l = t & 63, w = t >> 6;
    const unsigned short* Ab = A + (size_t)b * sA;
    const unsigned short* Bb = Bt + (size_t)b * sB;

    __shared__ __align__(16) unsigned short As[128 * 64];
    __shared__ __align__(16) unsigned short Bs[128 * 64];

    f32x4 acc[4][4] = {};
    const int wm = w >> 1, wn = w & 1;

    const int srow = t >> 3;                     // 0..31
    const int skc  = t & 7;                      // LDS k-chunk slot
    const int gkc  = skc ^ (srow & 7);           // swizzled global k-chunk

    const int lr = l & 15;                       // frag row within 16
    const int kq = l >> 4;                       // k-quarter 0..3
    const int xorv = lr & 7;                     // read-side swizzle

    for (int k0 = 0; k0 < 384; k0 += 64) {
#pragma unroll
        for (int j = 0; j < 4; ++j)
            __builtin_amdgcn_global_load_lds(
                (gbl_void*)(Ab + (size_t)(m0 + 32 * j + srow) * 384 + k0 + gkc * 8),
                (lds_void*)(As + (32 * j + srow) * 64 + skc * 8), 16, 0, 0);
#pragma unroll
        for (int j = 0; j < 4; ++j)
            __builtin_amdgcn_global_load_lds(
                (gbl_void*)(Bb + (size_t)(n0 + 32 * j + srow) * 384 + k0 + gkc * 8),
                (lds_void*)(Bs + (32 * j + srow) * 64 + skc * 8), 16, 0, 0);
        __syncthreads();

#pragma unroll
        for (int sub = 0; sub < 2; ++sub) {
            const int kc = sub * 4 + kq;                 // global k-chunk wanted
            const int ko = (kc ^ xorv) * 8;              // swizzled LDS offset
            bf16x8 af[4], bfr[4];
#pragma unroll
            for (int f = 0; f < 4; ++f)
                af[f] = *reinterpret_cast<const bf16x8*>(&As[(wm * 64 + f * 16 + lr) * 64 + ko]);
#pragma unroll
            for (int f = 0; f < 4; ++f)
                bfr[f] = *reinterpret_cast<const bf16x8*>(&Bs[(wn * 64 + f * 16 + lr) * 64 + ko]);
#pragma unroll
            for (int fm = 0; fm < 4; ++fm)
#pragma unroll
                for (int fn = 0; fn < 4; ++fn)
                    acc[fm][fn] = __builtin_amdgcn_mfma_f32_16x16x32_bf16(af[fm], bfr[fn], acc[fm][fn], 0, 0, 0);
        }
        __syncthreads();
    }

    const int lg = (l >> 4) * 4;
#pragma unroll
    for (int fm = 0; fm < 4; ++fm) {
        const int row = m0 + wm * 64 + fm * 16 + lg;
#pragma unroll
        for (int fn = 0; fn < 4; ++fn) {
            const int col = n0 + wn * 64 + fn * 16 + lr;
            const float cb = BIAS_COL ? bias[col] : 0.f;
#pragma unroll
            for (int rr = 0; rr < 4; ++rr) {
                const float v = acc[fm][fn][rr] + (BIAS_COL ? cb : bias[row + rr]);
                if (OUT_BF16)
                    ((unsigned short*)Yv)[(size_t)b * sY + (size_t)(row + rr) * N + col] = f2bf(v);
                else
                    ((float*)Yv)[(size_t)b * sY + (size_t)(row + rr) * N + col] = v;
            }
        }
    }
}

// ---------------------------------------------------------------------------
// depthwise dynamic 3x3 (channel-last), one thread = one pixel x 8 channels.
// grid (432, 16).
// ---------------------------------------------------------------------------
__global__ __launch_bounds__(256) void dwT_kernel(const unsigned short* __restrict__ vT,
                                                  const unsigned short* __restrict__ kT,
                                                  unsigned short* __restrict__ oT) {
    const int b = blockIdx.y;
    int u = blockIdx.x * 256 + threadIdx.x;
    const int cg = u % 48;
    const int p  = u / 48;
    const int h = p / W_, w = p % W_;
    const int c0 = cg * 8;
    const size_t base = (size_t)b * HW_ * C_;

    u16x8 kv[9];
#pragma unroll
    for (int q = 0; q < 9; ++q)
        kv[q] = *(const u16x8*)&kT[((size_t)b * 9 + q) * C_ + c0];

    float acc[8] = {};
#pragma unroll
    for (int di = 0; di < 3; ++di) {
        const int hh = h + di - 1;
        if (hh < 0 || hh >= H_) continue;
#pragma unroll
        for (int dj = 0; dj < 3; ++dj) {
            const int wn = w + dj - 1;
            if (wn < 0 || wn >= W_) continue;
            const u16x8 v = *(const u16x8*)&vT[base + (size_t)(hh * W_ + wn) * C_ + c0];
            const int q = di * 3 + dj;
#pragma unroll
            for (int e = 0; e < 8; ++e)
                acc[e] = fmaf(bf2f(v[e]), bf2f(kv[q][e]), acc[e]);
        }
    }
    u16x8 o;
#pragma unroll
    for (int e = 0; e < 8; ++e) o[e] = f2bf(acc[e]);
    *(u16x8*)&oT[base + (size_t)p * C_ + c0] = o;
}

// ---------------------------------------------------------------------------
extern "C" void kernel_launch(void* const* d_in, const int* in_sizes, int n_in,
                              void* d_out, int out_size, void* d_ws, size_t ws_size,
                              hipStream_t stream) {
    const float* x  = (const float*)d_in[0];
    const float* Wq = (const float*)d_in[1];
    const float* bq = (const float*)d_in[2];
    const float* Wk = (const float*)d_in[3];
    const float* bk = (const float*)d_in[4];
    const float* Wv = (const float*)d_in[5];
    const float* bv = (const float*)d_in[6];
    const float* Wg = (const float*)d_in[7];
    const float* bg = (const float*)d_in[8];
    const float* Wp = (const float*)d_in[9];
    const float* bp = (const float*)d_in[10];
    float* out = (float*)d_out;

    char* ws = (char*)d_ws;
    const size_t bhwc2 = (size_t)B_ * HW_ * C_ * 2;          // 28,311,552 B
    unsigned short* xT     = (unsigned short*)ws;             // reused as out2T
    unsigned short* valueT = (unsigned short*)(ws + bhwc2);
    unsigned short* Wvb    = (unsigned short*)(ws + 2 * bhwc2);
    unsigned short* Wpb    = (unsigned short*)(ws + 2 * bhwc2 + 294912);
    float*          px     = (float*)(ws + 2 * bhwc2 + 2 * 294912);
    unsigned short* kernT  = (unsigned short*)(ws + 2 * bhwc2 + 2 * 294912 + 221184);
    unsigned short* out2T  = xT;   // xT dead after GEMM1

    hipMemsetAsync(px, 0, (size_t)B_ * C_ * 9 * sizeof(float), stream);
    castw2_kernel<<<288, 256, 0, stream>>>(Wv, Wvb, Wp, Wpb);
    tcast_pool_kernel<<<dim3(HW_ / 64, C_ / 64, B_), 256, 0, stream>>>(x, xT, px);
    small_kernel<<<dim3(3, B_), 128, 0, stream>>>(px, Wq, bq, Wk, bk, Wg, bg, kernT);

    // GEMM1: valueT[(b.p)][c] = xT[(b.p)][:] . Wv[c][:] + bv[c]
    gemm_bt<1, true, 0><<<864, 256, 0, stream>>>(
        xT, Wvb, bv, (void*)valueT, C_, 288, 3, 864, 0LL, 0LL, 0LL);

    dwT_kernel<<<dim3(432, B_), 256, 0, stream>>>(valueT, kernT, out2T);

    // GEMM2: out[b][c][p] = Wp[c][:] . out2T[b][p][:] + bp[c]
    gemm_bt<0, false, 1><<<864, 256, 0, stream>>>(
        Wpb, out2T, bp, (void*)out, HW_, 3, 18, 54,
        0LL, (long long)HW_ * C_, (long long)C_ * HW_);
}

// Round 8
// 137.832 us; speedup vs baseline: 1.1535x; 1.1535x over previous
//
#include <hip/hip_runtime.h>
#include <cstdint>
#include <cstddef>

// Problem constants
#define B_  16
#define C_  384
#define H_  48
#define W_  48
#define HW_ 2304        // 48*48

typedef __bf16 bf16x8 __attribute__((ext_vector_type(8)));
typedef float  f32x4  __attribute__((ext_vector_type(4)));
typedef unsigned short u16x8 __attribute__((ext_vector_type(8)));

typedef __attribute__((address_space(3))) void       lds_void;
typedef const __attribute__((address_space(1))) void gbl_void;

__device__ __forceinline__ unsigned short f2bf(float f) {
    union { float f; unsigned int u; } v; v.f = f;
    unsigned int r = v.u + 0x7fffu + ((v.u >> 16) & 1u);   // RNE
    return (unsigned short)(r >> 16);
}
__device__ __forceinline__ float bf2f(unsigned short u) {
    union { unsigned int u; float f; } v; v.u = ((unsigned int)u) << 16;
    return v.f;
}

// ---------------------------------------------------------------------------
// cast both weight matrices fp32 -> bf16 in one launch.
// ---------------------------------------------------------------------------
__global__ void castw2_kernel(const float* __restrict__ wv, unsigned short* __restrict__ dv,
                              const float* __restrict__ wp, unsigned short* __restrict__ dp) {
    const int blk = blockIdx.x;
    const float* s = (blk < 144) ? wv : wp;
    unsigned short* d = (blk < 144) ? dv : dp;
    const int i = ((blk < 144 ? blk : blk - 144) * 256 + threadIdx.x) * 4;
    const float4 v = *(const float4*)&s[i];
    ushort4 o; o.x = f2bf(v.x); o.y = f2bf(v.y); o.z = f2bf(v.z); o.w = f2bf(v.w);
    *(ushort4*)&d[i] = o;
}

// ---------------------------------------------------------------------------
// pool (R1-proven): per-(b,c) 3x3 adaptive avg pool from fp32 x + plane mean.
// ---------------------------------------------------------------------------
__global__ void pool_kernel(const float* __restrict__ x,
                            float* __restrict__ px, float* __restrict__ emb) {
    const int bc = blockIdx.x;
    const float* xp = x + (size_t)bc * HW_;
    const int t = threadIdx.x;
    __shared__ float red[4];

    float v[9];
#pragma unroll
    for (int r = 0; r < 9; ++r) {
        const int ri = r / 3, rj = r % 3;
        v[r] = xp[(ri * 16 + (t >> 4)) * W_ + rj * 16 + (t & 15)];
    }
    float total = 0.f;
#pragma unroll
    for (int r = 0; r < 9; ++r) {
        float s = v[r];
#pragma unroll
        for (int o = 32; o > 0; o >>= 1) s += __shfl_down(s, o);
        if ((t & 63) == 0) red[t >> 6] = s;
        __syncthreads();
        if (t == 0) {
            const float bs = red[0] + red[1] + red[2] + red[3];
            px[bc * 9 + r] = bs * (1.f / 256.f);
            total += bs;
        }
        __syncthreads();
    }
    if (t == 0) emb[bc] = total * (1.f / 2304.f);
}

// ---------------------------------------------------------------------------
// small projections -> kernT[b][q][c] bf16 (R1-style: explicit emb input).
// ---------------------------------------------------------------------------
__global__ void small_kernel(const float* __restrict__ px, const float* __restrict__ emb,
                             const float* __restrict__ Wq, const float* __restrict__ bq,
                             const float* __restrict__ Wk, const float* __restrict__ bk,
                             const float* __restrict__ Wg, const float* __restrict__ bg,
                             unsigned short* __restrict__ kernT) {
    const int b = blockIdx.y;
    const int o = blockIdx.x * 128 + threadIdx.x;

    __shared__ float px_l[C_ * 9];
    __shared__ float emb_l[C_];
    __shared__ float wg_l[81];
    __shared__ float bg_l[9];

    for (int idx = threadIdx.x; idx < C_ * 9; idx += 128) px_l[idx] = px[(size_t)b * C_ * 9 + idx];
    for (int idx = threadIdx.x; idx < C_;     idx += 128) emb_l[idx] = emb[(size_t)b * C_ + idx];
    if (threadIdx.x < 81) wg_l[threadIdx.x] = Wg[threadIdx.x];
    if (threadIdx.x < 9)  bg_l[threadIdx.x] = bg[threadIdx.x];
    __syncthreads();

    float accq[9];
#pragma unroll
    for (int p = 0; p < 9; ++p) accq[p] = bq[o];
    float acck = bk[o];
    const float* wq_row = Wq + (size_t)o * C_;
    const float* wk_row = Wk + (size_t)o * C_;
    for (int i = 0; i < C_; ++i) {
        const float w = wq_row[i];
#pragma unroll
        for (int p = 0; p < 9; ++p) accq[p] = fmaf(w, px_l[i * 9 + p], accq[p]);
        acck = fmaf(wk_row[i], emb_l[i], acck);
    }

    float kf[9], mean = 0.f;
#pragma unroll
    for (int q = 0; q < 9; ++q) {
        float a = bg_l[q];
#pragma unroll
        for (int p = 0; p < 9; ++p) a = fmaf(accq[p], wg_l[q * 9 + p], a);
        kf[q] = a; mean += a;
    }
    mean *= (1.f / 9.f);
    const float sig = 1.f / (1.f + expf(-acck));
#pragma unroll
    for (int q = 0; q < 9; ++q)
        kernT[((size_t)b * 9 + q) * C_ + o] = f2bf(kf[q] - sig * mean);
}

// ---------------------------------------------------------------------------
// GEMM1 with fused transpose-cast A-staging:
// valueT[(b.p)][c_out] = sum_c bf16(x[b][c][p]) * Wv[c_out][c] + bv[c_out]
// A-tile staged from fp32 x (k-major) via reg: 8 dwordx4 loads -> cast ->
// 4 ds_write_b128 into swizzled [p][c] layout (chunk ^= p&7, matches read).
// B = Wvb via global_load_lds (R4 pattern).  Structure: R4 1-phase, BK=64.
// grid 864 XCD-swizzled; mtile = r/3, ntile = r%3 (b folded in M).
// ---------------------------------------------------------------------------
__global__ __launch_bounds__(256) void gemm_xA(const float* __restrict__ x,
                                               const unsigned short* __restrict__ Bt,
                                               const float* __restrict__ bias,
                                               unsigned short* __restrict__ Yv) {
    const int q8  = gridDim.x >> 3;
    const int swz = (blockIdx.x & 7) * q8 + (blockIdx.x >> 3);
    const int mtile = swz / 3;
    const int ntile = swz % 3;
    const int m0 = mtile * 128, n0 = ntile * 128;
    const int b  = m0 / HW_;            // tiles never cross batch (2304 = 18*128)
    const int p0 = m0 % HW_;

    const int t = threadIdx.x;
    const int l = t & 63, w = t >> 6;

    __shared__ __align__(16) unsigned short As[128 * 64];
    __shared__ __align__(16) unsigned short Bs[128 * 64];

    f32x4 acc[4][4] = {};
    const int wm = w >> 1, wn = w & 1;

    // B staging (global_load_lds, R4 pattern)
    const int srowB = t >> 3;                    // 0..31
    const int skc   = t & 7;
    const int gkc   = skc ^ (srowB & 7);

    // A staging (reg path): thread covers 8 consecutive c x 4 consecutive p
    const int cg = t & 7;                        // c-chunk (8 c each)
    const int pc = t >> 3;                       // 0..31 -> p_local = pc*4 + i
    const float* xAbase = x + ((size_t)b * C_ + cg * 8) * HW_ + p0 + pc * 4;

    // fragment read indices (R4-identical)
    const int lr = l & 15;
    const int kq = l >> 4;
    const int xorv = lr & 7;

    for (int k0 = 0; k0 < 384; k0 += 64) {
        // B: 4 async global->LDS
#pragma unroll
        for (int j = 0; j < 4; ++j)
            __builtin_amdgcn_global_load_lds(
                (gbl_void*)(Bt + (size_t)(n0 + 32 * j + srowB) * 384 + k0 + gkc * 8),
                (lds_void*)(Bs + (32 * j + srowB) * 64 + skc * 8), 16, 0, 0);

        // A: 8 fp32 row-loads -> cast -> 4 swizzled b128 LDS writes
        float4 ld0 = *(const float4*)&xAbase[(size_t)(k0 + 0) * HW_];
        float4 ld1 = *(const float4*)&xAbase[(size_t)(k0 + 1) * HW_];
        float4 ld2 = *(const float4*)&xAbase[(size_t)(k0 + 2) * HW_];
        float4 ld3 = *(const float4*)&xAbase[(size_t)(k0 + 3) * HW_];
        float4 ld4 = *(const float4*)&xAbase[(size_t)(k0 + 4) * HW_];
        float4 ld5 = *(const float4*)&xAbase[(size_t)(k0 + 5) * HW_];
        float4 ld6 = *(const float4*)&xAbase[(size_t)(k0 + 6) * HW_];
        float4 ld7 = *(const float4*)&xAbase[(size_t)(k0 + 7) * HW_];
#pragma unroll
        for (int i = 0; i < 4; ++i) {
            const float e0 = (i == 0) ? ld0.x : (i == 1) ? ld0.y : (i == 2) ? ld0.z : ld0.w;
            const float e1 = (i == 0) ? ld1.x : (i == 1) ? ld1.y : (i == 2) ? ld1.z : ld1.w;
            const float e2 = (i == 0) ? ld2.x : (i == 1) ? ld2.y : (i == 2) ? ld2.z : ld2.w;
            const float e3 = (i == 0) ? ld3.x : (i == 1) ? ld3.y : (i == 2) ? ld3.z : ld3.w;
            const float e4 = (i == 0) ? ld4.x : (i == 1) ? ld4.y : (i == 2) ? ld4.z : ld4.w;
            const float e5 = (i == 0) ? ld5.x : (i == 1) ? ld5.y : (i == 2) ? ld5.z : ld5.w;
            const float e6 = (i == 0) ? ld6.x : (i == 1) ? ld6.y : (i == 2) ? ld6.z : ld6.w;
            const float e7 = (i == 0) ? ld7.x : (i == 1) ? ld7.y : (i == 2) ? ld7.z : ld7.w;
            u16x8 pk;
            pk[0] = f2bf(e0); pk[1] = f2bf(e1); pk[2] = f2bf(e2); pk[3] = f2bf(e3);
            pk[4] = f2bf(e4); pk[5] = f2bf(e5); pk[6] = f2bf(e6); pk[7] = f2bf(e7);
            const int pl = pc * 4 + i;
            *(u16x8*)&As[pl * 64 + ((cg ^ (pl & 7)) * 8)] = pk;
        }
        __syncthreads();   // drains vmcnt (B) + lgkmcnt (A writes), then barrier

#pragma unroll
        for (int sub = 0; sub < 2; ++sub) {
            const int kc = sub * 4 + kq;
            const int ko = (kc ^ xorv) * 8;
            bf16x8 af[4], bfr[4];
#pragma unroll
            for (int f = 0; f < 4; ++f)
                af[f] = *reinterpret_cast<const bf16x8*>(&As[(wm * 64 + f * 16 + lr) * 64 + ko]);
#pragma unroll
            for (int f = 0; f < 4; ++f)
                bfr[f] = *reinterpret_cast<const bf16x8*>(&Bs[(wn * 64 + f * 16 + lr) * 64 + ko]);
#pragma unroll
            for (int fm = 0; fm < 4; ++fm)
#pragma unroll
                for (int fn = 0; fn < 4; ++fn)
                    acc[fm][fn] = __builtin_amdgcn_mfma_f32_16x16x32_bf16(af[fm], bfr[fn], acc[fm][fn], 0, 0, 0);
        }
        __syncthreads();
    }

    const int lg = (l >> 4) * 4;
#pragma unroll
    for (int fm = 0; fm < 4; ++fm) {
        const int row = m0 + wm * 64 + fm * 16 + lg;       // global (b.p) row
#pragma unroll
        for (int fn = 0; fn < 4; ++fn) {
            const int col = n0 + wn * 64 + fn * 16 + lr;   // c_out
            const float cb = bias[col];
#pragma unroll
            for (int rr = 0; rr < 4; ++rr)
                Yv[(size_t)(row + rr) * C_ + col] = f2bf(acc[fm][fn][rr] + cb);
        }
    }
}

// ---------------------------------------------------------------------------
// bf16 MFMA GEMM (R4-exact), BK=64, swizzled, XCD-chunked — used for GEMM2.
// ---------------------------------------------------------------------------
template<int BIAS_COL, bool OUT_BF16, int BMAJOR>
__global__ __launch_bounds__(256) void gemm_bt(const unsigned short* __restrict__ A,
                                               const unsigned short* __restrict__ Bt,
                                               const float* __restrict__ bias,
                                               void* __restrict__ Yv,
                                               int N, int nMt, int nNt, int perB,
                                               long long sA, long long sB, long long sY) {
    const int q8  = gridDim.x >> 3;
    const int swz = (blockIdx.x & 7) * q8 + (blockIdx.x >> 3);
    const int b   = swz / perB;
    const int r   = swz % perB;
    const int mtile = BMAJOR ? (r % nMt) : (r / nNt);
    const int ntile = BMAJOR ? (r / nMt) : (r % nNt);
    const int m0 = mtile * 128, n0 = ntile * 128;

    const int t = threadIdx.x;
    const int l = t & 63, w = t >> 6;
    const unsigned short* Ab = A + (size_t)b * sA;
    const unsigned short* Bb = Bt + (size_t)b * sB;

    __shared__ __align__(16) unsigned short As[128 * 64];
    __shared__ __align__(16) unsigned short Bs[128 * 64];

    f32x4 acc[4][4] = {};
    const int wm = w >> 1, wn = w & 1;

    const int srow = t >> 3;
    const int skc  = t & 7;
    const int gkc  = skc ^ (srow & 7);

    const int lr = l & 15;
    const int kq = l >> 4;
    const int xorv = lr & 7;

    for (int k0 = 0; k0 < 384; k0 += 64) {
#pragma unroll
        for (int j = 0; j < 4; ++j)
            __builtin_amdgcn_global_load_lds(
                (gbl_void*)(Ab + (size_t)(m0 + 32 * j + srow) * 384 + k0 + gkc * 8),
                (lds_void*)(As + (32 * j + srow) * 64 + skc * 8), 16, 0, 0);
#pragma unroll
        for (int j = 0; j < 4; ++j)
            __builtin_amdgcn_global_load_lds(
                (gbl_void*)(Bb + (size_t)(n0 + 32 * j + srow) * 384 + k0 + gkc * 8),
                (lds_void*)(Bs + (32 * j + srow) * 64 + skc * 8), 16, 0, 0);
        __syncthreads();

#pragma unroll
        for (int sub = 0; sub < 2; ++sub) {
            const int kc = sub * 4 + kq;
            const int ko = (kc ^ xorv) * 8;
            bf16x8 af[4], bfr[4];
#pragma unroll
            for (int f = 0; f < 4; ++f)
                af[f] = *reinterpret_cast<const bf16x8*>(&As[(wm * 64 + f * 16 + lr) * 64 + ko]);
#pragma unroll
            for (int f = 0; f < 4; ++f)
                bfr[f] = *reinterpret_cast<const bf16x8*>(&Bs[(wn * 64 + f * 16 + lr) * 64 + ko]);
#pragma unroll
            for (int fm = 0; fm < 4; ++fm)
#pragma unroll
                for (int fn = 0; fn < 4; ++fn)
                    acc[fm][fn] = __builtin_amdgcn_mfma_f32_16x16x32_bf16(af[fm], bfr[fn], acc[fm][fn], 0, 0, 0);
        }
        __syncthreads();
    }

    const int lg = (l >> 4) * 4;
#pragma unroll
    for (int fm = 0; fm < 4; ++fm) {
        const int row = m0 + wm * 64 + fm * 16 + lg;
#pragma unroll
        for (int fn = 0; fn < 4; ++fn) {
            const int col = n0 + wn * 64 + fn * 16 + lr;
            const float cb = BIAS_COL ? bias[col] : 0.f;
#pragma unroll
            for (int rr = 0; rr < 4; ++rr) {
                const float v = acc[fm][fn][rr] + (BIAS_COL ? cb : bias[row + rr]);
                if (OUT_BF16)
                    ((unsigned short*)Yv)[(size_t)b * sY + (size_t)(row + rr) * N + col] = f2bf(v);
                else
                    ((float*)Yv)[(size_t)b * sY + (size_t)(row + rr) * N + col] = v;
            }
        }
    }
}

// ---------------------------------------------------------------------------
// depthwise dynamic 3x3 (channel-last), one thread = one pixel x 8 channels.
// ---------------------------------------------------------------------------
__global__ __launch_bounds__(256) void dwT_kernel(const unsigned short* __restrict__ vT,
                                                  const unsigned short* __restrict__ kT,
                                                  unsigned short* __restrict__ oT) {
    const int b = blockIdx.y;
    int u = blockIdx.x * 256 + threadIdx.x;
    const int cg = u % 48;
    const int p  = u / 48;
    const int h = p / W_, w = p % W_;
    const int c0 = cg * 8;
    const size_t base = (size_t)b * HW_ * C_;

    u16x8 kv[9];
#pragma unroll
    for (int q = 0; q < 9; ++q)
        kv[q] = *(const u16x8*)&kT[((size_t)b * 9 + q) * C_ + c0];

    float acc[8] = {};
#pragma unroll
    for (int di = 0; di < 3; ++di) {
        const int hh = h + di - 1;
        if (hh < 0 || hh >= H_) continue;
#pragma unroll
        for (int dj = 0; dj < 3; ++dj) {
            const int wn = w + dj - 1;
            if (wn < 0 || wn >= W_) continue;
            const u16x8 v = *(const u16x8*)&vT[base + (size_t)(hh * W_ + wn) * C_ + c0];
            const int q = di * 3 + dj;
#pragma unroll
            for (int e = 0; e < 8; ++e)
                acc[e] = fmaf(bf2f(v[e]), bf2f(kv[q][e]), acc[e]);
        }
    }
    u16x8 o;
#pragma unroll
    for (int e = 0; e < 8; ++e) o[e] = f2bf(acc[e]);
    *(u16x8*)&oT[base + (size_t)p * C_ + c0] = o;
}

// ---------------------------------------------------------------------------
extern "C" void kernel_launch(void* const* d_in, const int* in_sizes, int n_in,
                              void* d_out, int out_size, void* d_ws, size_t ws_size,
                              hipStream_t stream) {
    const float* x  = (const float*)d_in[0];
    const float* Wq = (const float*)d_in[1];
    const float* bq = (const float*)d_in[2];
    const float* Wk = (const float*)d_in[3];
    const float* bk = (const float*)d_in[4];
    const float* Wv = (const float*)d_in[5];
    const float* bv = (const float*)d_in[6];
    const float* Wg = (const float*)d_in[7];
    const float* bg = (const float*)d_in[8];
    const float* Wp = (const float*)d_in[9];
    const float* bp = (const float*)d_in[10];
    float* out = (float*)d_out;

    char* ws = (char*)d_ws;
    const size_t bhwc2 = (size_t)B_ * HW_ * C_ * 2;          // 28,311,552 B
    unsigned short* scratchT = (unsigned short*)ws;           // emb (early) / out2T (late)
    unsigned short* valueT = (unsigned short*)(ws + bhwc2);
    unsigned short* Wvb    = (unsigned short*)(ws + 2 * bhwc2);
    unsigned short* Wpb    = (unsigned short*)(ws + 2 * bhwc2 + 294912);
    float*          px     = (float*)(ws + 2 * bhwc2 + 2 * 294912);
    unsigned short* kernT  = (unsigned short*)(ws + 2 * bhwc2 + 2 * 294912 + 221184);

    float*          emb    = (float*)scratchT;  // first 24.6 KB, dead before out2T use
    unsigned short* out2T  = scratchT;

    castw2_kernel<<<288, 256, 0, stream>>>(Wv, Wvb, Wp, Wpb);
    pool_kernel<<<B_ * C_, 256, 0, stream>>>(x, px, emb);
    small_kernel<<<dim3(3, B_), 128, 0, stream>>>(px, emb, Wq, bq, Wk, bk, Wg, bg, kernT);

    // GEMM1 (fused transpose-cast A): valueT[(b.p)][c] = bf16(x)·Wv + bv
    gemm_xA<<<864, 256, 0, stream>>>(x, Wvb, bv, valueT);

    dwT_kernel<<<dim3(432, B_), 256, 0, stream>>>(valueT, kernT, out2T);

    // GEMM2: out[b][c][p] = Wp[c][:] . out2T[b][p][:] + bp[c]
    gemm_bt<0, false, 1><<<864, 256, 0, stream>>>(
        Wpb, out2T, bp, (void*)out, HW_, 3, 18, 54,
        0LL, (long long)HW_ * C_, (long long)C_ * HW_);
}

// Round 9
// 130.707 us; speedup vs baseline: 1.2164x; 1.0545x over previous
//
#include <hip/hip_runtime.h>
#include <cstdint>
#include <cstddef>

// Problem constants
#define B_  16
#define C_  384
#define H_  48
#define W_  48
#define HW_ 2304        // 48*48

typedef __bf16 bf16x8 __attribute__((ext_vector_type(8)));
typedef float  f32x4  __attribute__((ext_vector_type(4)));
typedef unsigned short u16x8 __attribute__((ext_vector_type(8)));

typedef __attribute__((address_space(3))) void       lds_void;
typedef const __attribute__((address_space(1))) void gbl_void;

__device__ __forceinline__ unsigned short f2bf(float f) {
    union { float f; unsigned int u; } v; v.f = f;
    unsigned int r = v.u + 0x7fffu + ((v.u >> 16) & 1u);   // RNE
    return (unsigned short)(r >> 16);
}
__device__ __forceinline__ float bf2f(unsigned short u) {
    union { unsigned int u; float f; } v; v.u = ((unsigned int)u) << 16;
    return v.f;
}

// ---------------------------------------------------------------------------
// prep: ONE launch doing three independent proven jobs, partitioned by block:
//   blocks [0,3456)      : tcast  x[b][c][p] fp32 -> xT[b][p][c] bf16
//   blocks [3456,9600)   : pool   (R1-proven fp32 body) -> px, emb
//   blocks [9600,9888)   : castw2 Wv,Wp fp32 -> bf16
// ---------------------------------------------------------------------------
__global__ __launch_bounds__(256) void prep_kernel(const float* __restrict__ x,
                                                   const float* __restrict__ Wv,
                                                   const float* __restrict__ Wp,
                                                   unsigned short* __restrict__ Wvb,
                                                   unsigned short* __restrict__ Wpb,
                                                   unsigned short* __restrict__ xT,
                                                   float* __restrict__ px,
                                                   float* __restrict__ emb) {
    __shared__ unsigned short tile[64][68];
    __shared__ float red[4];
    const int blk = blockIdx.x;
    const int t   = threadIdx.x;

    if (blk < 3456) {
        // ---- tcast (R4-exact body) ----
        const int b    = blk / 216;
        const int r216 = blk % 216;
        const int c0   = (r216 / 36) * 64;
        const int p0   = (r216 % 36) * 64;
        const float* xb = x + ((size_t)b * C_ + c0) * HW_ + p0;

#pragma unroll
        for (int pass = 0; pass < 4; ++pass) {
            const int cr = pass * 16 + (t >> 4);
            const int pc = (t & 15) * 4;
            const float4 v = *(const float4*)&xb[(size_t)cr * HW_ + pc];
            tile[pc + 0][cr] = f2bf(v.x); tile[pc + 1][cr] = f2bf(v.y);
            tile[pc + 2][cr] = f2bf(v.z); tile[pc + 3][cr] = f2bf(v.w);
        }
        __syncthreads();
        unsigned short* xTb = xT + ((size_t)b * HW_ + p0) * C_ + c0;
#pragma unroll
        for (int pass = 0; pass < 4; ++pass) {
            const int pr = pass * 16 + (t >> 4);
            const int cc = (t & 15) * 4;
            *(ushort4*)&xTb[(size_t)pr * C_ + cc] = *(const ushort4*)&tile[pr][cc];
        }
    } else if (blk < 9600) {
        // ---- pool (R1/R8-proven fp32 body) ----
        const int bc = blk - 3456;
        const float* xp = x + (size_t)bc * HW_;

        float v[9];
#pragma unroll
        for (int r = 0; r < 9; ++r) {
            const int ri = r / 3, rj = r % 3;
            v[r] = xp[(ri * 16 + (t >> 4)) * W_ + rj * 16 + (t & 15)];
        }
        float total = 0.f;
#pragma unroll
        for (int r = 0; r < 9; ++r) {
            float s = v[r];
#pragma unroll
            for (int o = 32; o > 0; o >>= 1) s += __shfl_down(s, o);
            if ((t & 63) == 0) red[t >> 6] = s;
            __syncthreads();
            if (t == 0) {
                const float bs = red[0] + red[1] + red[2] + red[3];
                px[bc * 9 + r] = bs * (1.f / 256.f);
                total += bs;
            }
            __syncthreads();
        }
        if (t == 0) emb[bc] = total * (1.f / 2304.f);
    } else {
        // ---- castw2 (R4-exact body) ----
        const int cblk = blk - 9600;
        const float* s = (cblk < 144) ? Wv : Wp;
        unsigned short* d = (cblk < 144) ? Wvb : Wpb;
        const int i = ((cblk < 144 ? cblk : cblk - 144) * 256 + t) * 4;
        const float4 v = *(const float4*)&s[i];
        ushort4 o; o.x = f2bf(v.x); o.y = f2bf(v.y); o.z = f2bf(v.z); o.w = f2bf(v.w);
        *(ushort4*)&d[i] = o;
    }
}

// ---------------------------------------------------------------------------
// small projections -> kernT[b][q][c] bf16 (R1-proven, explicit emb input).
// ---------------------------------------------------------------------------
__global__ void small_kernel(const float* __restrict__ px, const float* __restrict__ emb,
                             const float* __restrict__ Wq, const float* __restrict__ bq,
                             const float* __restrict__ Wk, const float* __restrict__ bk,
                             const float* __restrict__ Wg, const float* __restrict__ bg,
                             unsigned short* __restrict__ kernT) {
    const int b = blockIdx.y;
    const int o = blockIdx.x * 128 + threadIdx.x;

    __shared__ float px_l[C_ * 9];
    __shared__ float emb_l[C_];
    __shared__ float wg_l[81];
    __shared__ float bg_l[9];

    for (int idx = threadIdx.x; idx < C_ * 9; idx += 128) px_l[idx] = px[(size_t)b * C_ * 9 + idx];
    for (int idx = threadIdx.x; idx < C_;     idx += 128) emb_l[idx] = emb[(size_t)b * C_ + idx];
    if (threadIdx.x < 81) wg_l[threadIdx.x] = Wg[threadIdx.x];
    if (threadIdx.x < 9)  bg_l[threadIdx.x] = bg[threadIdx.x];
    __syncthreads();

    float accq[9];
#pragma unroll
    for (int p = 0; p < 9; ++p) accq[p] = bq[o];
    float acck = bk[o];
    const float* wq_row = Wq + (size_t)o * C_;
    const float* wk_row = Wk + (size_t)o * C_;
    for (int i = 0; i < C_; ++i) {
        const float w = wq_row[i];
#pragma unroll
        for (int p = 0; p < 9; ++p) accq[p] = fmaf(w, px_l[i * 9 + p], accq[p]);
        acck = fmaf(wk_row[i], emb_l[i], acck);
    }

    float kf[9], mean = 0.f;
#pragma unroll
    for (int q = 0; q < 9; ++q) {
        float a = bg_l[q];
#pragma unroll
        for (int p = 0; p < 9; ++p) a = fmaf(accq[p], wg_l[q * 9 + p], a);
        kf[q] = a; mean += a;
    }
    mean *= (1.f / 9.f);
    const float sig = 1.f / (1.f + expf(-acck));
#pragma unroll
    for (int q = 0; q < 9; ++q)
        kernT[((size_t)b * 9 + q) * C_ + o] = f2bf(kf[q] - sig * mean);
}

// ---------------------------------------------------------------------------
// bf16 MFMA GEMM (R4-exact): BK=64, XOR-swizzled LDS, XCD-chunked 1-D grid.
// ---------------------------------------------------------------------------
template<int BIAS_COL, bool OUT_BF16, int BMAJOR>
__global__ __launch_bounds__(256) void gemm_bt(const unsigned short* __restrict__ A,
                                               const unsigned short* __restrict__ Bt,
                                               const float* __restrict__ bias,
                                               void* __restrict__ Yv,
                                               int N, int nMt, int nNt, int perB,
                                               long long sA, long long sB, long long sY) {
    const int q8  = gridDim.x >> 3;
    const int swz = (blockIdx.x & 7) * q8 + (blockIdx.x >> 3);
    const int b   = swz / perB;
    const int r   = swz % perB;
    const int mtile = BMAJOR ? (r % nMt) : (r / nNt);
    const int ntile = BMAJOR ? (r / nMt) : (r % nNt);
    const int m0 = mtile * 128, n0 = ntile * 128;

    const int t = threadIdx.x;
    const int l = t & 63, w = t >> 6;
    const unsigned short* Ab = A + (size_t)b * sA;
    const unsigned short* Bb = Bt + (size_t)b * sB;

    __shared__ __align__(16) unsigned short As[128 * 64];
    __shared__ __align__(16) unsigned short Bs[128 * 64];

    f32x4 acc[4][4] = {};
    const int wm = w >> 1, wn = w & 1;

    const int srow = t >> 3;
    const int skc  = t & 7;
    const int gkc  = skc ^ (srow & 7);

    const int lr = l & 15;
    const int kq = l >> 4;
    const int xorv = lr & 7;

    for (int k0 = 0; k0 < 384; k0 += 64) {
#pragma unroll
        for (int j = 0; j < 4; ++j)
            __builtin_amdgcn_global_load_lds(
                (gbl_void*)(Ab + (size_t)(m0 + 32 * j + srow) * 384 + k0 + gkc * 8),
                (lds_void*)(As + (32 * j + srow) * 64 + skc * 8), 16, 0, 0);
#pragma unroll
        for (int j = 0; j < 4; ++j)
            __builtin_amdgcn_global_load_lds(
                (gbl_void*)(Bb + (size_t)(n0 + 32 * j + srow) * 384 + k0 + gkc * 8),
                (lds_void*)(Bs + (32 * j + srow) * 64 + skc * 8), 16, 0, 0);
        __syncthreads();

#pragma unroll
        for (int sub = 0; sub < 2; ++sub) {
            const int kc = sub * 4 + kq;
            const int ko = (kc ^ xorv) * 8;
            bf16x8 af[4], bfr[4];
#pragma unroll
            for (int f = 0; f < 4; ++f)
                af[f] = *reinterpret_cast<const bf16x8*>(&As[(wm * 64 + f * 16 + lr) * 64 + ko]);
#pragma unroll
            for (int f = 0; f < 4; ++f)
                bfr[f] = *reinterpret_cast<const bf16x8*>(&Bs[(wn * 64 + f * 16 + lr) * 64 + ko]);
#pragma unroll
            for (int fm = 0; fm < 4; ++fm)
#pragma unroll
                for (int fn = 0; fn < 4; ++fn)
                    acc[fm][fn] = __builtin_amdgcn_mfma_f32_16x16x32_bf16(af[fm], bfr[fn], acc[fm][fn], 0, 0, 0);
        }
        __syncthreads();
    }

    const int lg = (l >> 4) * 4;
#pragma unroll
    for (int fm = 0; fm < 4; ++fm) {
        const int row = m0 + wm * 64 + fm * 16 + lg;
#pragma unroll
        for (int fn = 0; fn < 4; ++fn) {
            const int col = n0 + wn * 64 + fn * 16 + lr;
            const float cb = BIAS_COL ? bias[col] : 0.f;
#pragma unroll
            for (int rr = 0; rr < 4; ++rr) {
                const float v = acc[fm][fn][rr] + (BIAS_COL ? cb : bias[row + rr]);
                if (OUT_BF16)
                    ((unsigned short*)Yv)[(size_t)b * sY + (size_t)(row + rr) * N + col] = f2bf(v);
                else
                    ((float*)Yv)[(size_t)b * sY + (size_t)(row + rr) * N + col] = v;
            }
        }
    }
}

// ---------------------------------------------------------------------------
// depthwise dynamic 3x3 (channel-last), one thread = one pixel x 8 channels.
// ---------------------------------------------------------------------------
__global__ __launch_bounds__(256) void dwT_kernel(const unsigned short* __restrict__ vT,
                                                  const unsigned short* __restrict__ kT,
                                                  unsigned short* __restrict__ oT) {
    const int b = blockIdx.y;
    int u = blockIdx.x * 256 + threadIdx.x;
    const int cg = u % 48;
    const int p  = u / 48;
    const int h = p / W_, w = p % W_;
    const int c0 = cg * 8;
    const size_t base = (size_t)b * HW_ * C_;

    u16x8 kv[9];
#pragma unroll
    for (int q = 0; q < 9; ++q)
        kv[q] = *(const u16x8*)&kT[((size_t)b * 9 + q) * C_ + c0];

    float acc[8] = {};
#pragma unroll
    for (int di = 0; di < 3; ++di) {
        const int hh = h + di - 1;
        if (hh < 0 || hh >= H_) continue;
#pragma unroll
        for (int dj = 0; dj < 3; ++dj) {
            const int wn = w + dj - 1;
            if (wn < 0 || wn >= W_) continue;
            const u16x8 v = *(const u16x8*)&vT[base + (size_t)(hh * W_ + wn) * C_ + c0];
            const int q = di * 3 + dj;
#pragma unroll
            for (int e = 0; e < 8; ++e)
                acc[e] = fmaf(bf2f(v[e]), bf2f(kv[q][e]), acc[e]);
        }
    }
    u16x8 o;
#pragma unroll
    for (int e = 0; e < 8; ++e) o[e] = f2bf(acc[e]);
    *(u16x8*)&oT[base + (size_t)p * C_ + c0] = o;
}

// ---------------------------------------------------------------------------
extern "C" void kernel_launch(void* const* d_in, const int* in_sizes, int n_in,
                              void* d_out, int out_size, void* d_ws, size_t ws_size,
                              hipStream_t stream) {
    const float* x  = (const float*)d_in[0];
    const float* Wq = (const float*)d_in[1];
    const float* bq = (const float*)d_in[2];
    const float* Wk = (const float*)d_in[3];
    const float* bk = (const float*)d_in[4];
    const float* Wv = (const float*)d_in[5];
    const float* bv = (const float*)d_in[6];
    const float* Wg = (const float*)d_in[7];
    const float* bg = (const float*)d_in[8];
    const float* Wp = (const float*)d_in[9];
    const float* bp = (const float*)d_in[10];
    float* out = (float*)d_out;

    char* ws = (char*)d_ws;
    const size_t bhwc2 = (size_t)B_ * HW_ * C_ * 2;          // 28,311,552 B
    unsigned short* xT     = (unsigned short*)ws;             // reused as out2T
    unsigned short* valueT = (unsigned short*)(ws + bhwc2);
    unsigned short* Wvb    = (unsigned short*)(ws + 2 * bhwc2);
    unsigned short* Wpb    = (unsigned short*)(ws + 2 * bhwc2 + 294912);
    float*          px     = (float*)(ws + 2 * bhwc2 + 2 * 294912);
    unsigned short* kernT  = (unsigned short*)(ws + 2 * bhwc2 + 2 * 294912 + 221184);
    float*          emb    = (float*)(ws + 2 * bhwc2 + 2 * 294912 + 221184 + 110592);
    unsigned short* out2T  = xT;   // xT dead after GEMM1

    // 1. fused prep: tcast + pool + weight-cast in one launch
    prep_kernel<<<9888, 256, 0, stream>>>(x, Wv, Wp, Wvb, Wpb, xT, px, emb);
    // 2. dynamic kernels
    small_kernel<<<dim3(3, B_), 128, 0, stream>>>(px, emb, Wq, bq, Wk, bk, Wg, bg, kernT);
    // 3. GEMM1: valueT[(b.p)][c] = xT[(b.p)][:] . Wv[c][:] + bv[c]
    gemm_bt<1, true, 0><<<864, 256, 0, stream>>>(
        xT, Wvb, bv, (void*)valueT, C_, 288, 3, 864, 0LL, 0LL, 0LL);
    // 4. depthwise dynamic 3x3
    dwT_kernel<<<dim3(432, B_), 256, 0, stream>>>(valueT, kernT, out2T);
    // 5. GEMM2: out[b][c][p] = Wp[c][:] . out2T[b][p][:] + bp[c]
    gemm_bt<0, false, 1><<<864, 256, 0, stream>>>(
        Wpb, out2T, bp, (void*)out, HW_, 3, 18, 54,
        0LL, (long long)HW_ * C_, (long long)C_ * HW_);
}

// Round 10
// 116.335 us; speedup vs baseline: 1.3667x; 1.1235x over previous
//
#include <hip/hip_runtime.h>
#include <cstdint>
#include <cstddef>

// Problem constants
#define B_  16
#define C_  384
#define H_  48
#define W_  48
#define HW_ 2304        // 48*48

typedef __bf16 bf16x8 __attribute__((ext_vector_type(8)));
typedef float  f32x4  __attribute__((ext_vector_type(4)));
typedef unsigned short u16x8 __attribute__((ext_vector_type(8)));

typedef __attribute__((address_space(3))) void       lds_void;
typedef const __attribute__((address_space(1))) void gbl_void;

__device__ __forceinline__ unsigned short f2bf(float f) {
    union { float f; unsigned int u; } v; v.f = f;
    unsigned int r = v.u + 0x7fffu + ((v.u >> 16) & 1u);   // RNE
    return (unsigned short)(r >> 16);
}
__device__ __forceinline__ float bf2f(unsigned short u) {
    union { unsigned int u; float f; } v; v.u = ((unsigned int)u) << 16;
    return v.f;
}

// ---------------------------------------------------------------------------
// tcastw: tcast + weight-cast in ONE launch, partitioned by block.
//   blocks [0,3456)    : x[b][c][p] fp32 -> xT[b][p][c] bf16 (R4-exact body)
//   blocks [3456,3744) : Wv,Wp fp32 -> bf16 (R4-exact castw2 body)
// ---------------------------------------------------------------------------
__global__ __launch_bounds__(256) void tcastw_kernel(const float* __restrict__ x,
                                                     const float* __restrict__ Wv,
                                                     const float* __restrict__ Wp,
                                                     unsigned short* __restrict__ Wvb,
                                                     unsigned short* __restrict__ Wpb,
                                                     unsigned short* __restrict__ xT) {
    __shared__ unsigned short tile[64][68];
    const int blk = blockIdx.x;
    const int t   = threadIdx.x;

    if (blk < 3456) {
        const int b    = blk / 216;
        const int r216 = blk % 216;
        const int c0   = (r216 / 36) * 64;
        const int p0   = (r216 % 36) * 64;
        const float* xb = x + ((size_t)b * C_ + c0) * HW_ + p0;

#pragma unroll
        for (int pass = 0; pass < 4; ++pass) {
            const int cr = pass * 16 + (t >> 4);
            const int pc = (t & 15) * 4;
            const float4 v = *(const float4*)&xb[(size_t)cr * HW_ + pc];
            tile[pc + 0][cr] = f2bf(v.x); tile[pc + 1][cr] = f2bf(v.y);
            tile[pc + 2][cr] = f2bf(v.z); tile[pc + 3][cr] = f2bf(v.w);
        }
        __syncthreads();
        unsigned short* xTb = xT + ((size_t)b * HW_ + p0) * C_ + c0;
#pragma unroll
        for (int pass = 0; pass < 4; ++pass) {
            const int pr = pass * 16 + (t >> 4);
            const int cc = (t & 15) * 4;
            *(ushort4*)&xTb[(size_t)pr * C_ + cc] = *(const ushort4*)&tile[pr][cc];
        }
    } else {
        const int cblk = blk - 3456;
        const float* s = (cblk < 144) ? Wv : Wp;
        unsigned short* d = (cblk < 144) ? Wvb : Wpb;
        const int i = ((cblk < 144 ? cblk : cblk - 144) * 256 + t) * 4;
        const float4 v = *(const float4*)&s[i];
        ushort4 o; o.x = f2bf(v.x); o.y = f2bf(v.y); o.z = f2bf(v.z); o.w = f2bf(v.w);
        *(ushort4*)&d[i] = o;
    }
}

// ---------------------------------------------------------------------------
// poolT (R4-exact): 3x3 adaptive avg pool from xT (bf16). px[b][c][r].
// ---------------------------------------------------------------------------
__global__ __launch_bounds__(256) void poolT_kernel(const unsigned short* __restrict__ xT,
                                                    float* __restrict__ px) {
    const int r  = blockIdx.x;
    const int c0 = blockIdx.y * 64;
    const int b  = blockIdx.z;
    const int t  = threadIdx.x;
    const int wv = t >> 6;
    const int l  = t & 63;
    const int i  = l >> 3;
    const int cg = l & 7;
    const int ri = r / 3, rj = r % 3;
    const int cbase = c0 + cg * 8;

    __shared__ float s[4][64];

    float acc[8] = {};
#pragma unroll
    for (int k = 0; k < 8; ++k) {
        const int pix = wv * 64 + i + k * 8;
        const int h = ri * 16 + (pix >> 4), w = rj * 16 + (pix & 15);
        const u16x8 v = *(const u16x8*)&xT[((size_t)b * HW_ + h * W_ + w) * C_ + cbase];
#pragma unroll
        for (int e = 0; e < 8; ++e) acc[e] += bf2f(v[e]);
    }
#pragma unroll
    for (int m = 8; m <= 32; m <<= 1)
#pragma unroll
        for (int e = 0; e < 8; ++e) acc[e] += __shfl_xor(acc[e], m, 64);
    if (i == 0)
#pragma unroll
        for (int e = 0; e < 8; ++e) s[wv][cg * 8 + e] = acc[e];
    __syncthreads();
    if (t < 64) {
        const float tot = s[0][t] + s[1][t] + s[2][t] + s[3][t];
        px[((size_t)b * C_ + c0 + t) * 9 + r] = tot * (1.f / 256.f);
    }
}

// ---------------------------------------------------------------------------
// small projections -> kernT[b][q][c] bf16 (R4-exact, emb derived from px).
// ---------------------------------------------------------------------------
__global__ void small_kernel(const float* __restrict__ px,
                             const float* __restrict__ Wq, const float* __restrict__ bq,
                             const float* __restrict__ Wk, const float* __restrict__ bk,
                             const float* __restrict__ Wg, const float* __restrict__ bg,
                             unsigned short* __restrict__ kernT) {
    const int b = blockIdx.y;
    const int o = blockIdx.x * 128 + threadIdx.x;

    __shared__ float px_l[C_ * 9];
    __shared__ float emb_l[C_];
    __shared__ float wg_l[81];
    __shared__ float bg_l[9];

    for (int idx = threadIdx.x; idx < C_ * 9; idx += 128) px_l[idx] = px[(size_t)b * C_ * 9 + idx];
    if (threadIdx.x < 81) wg_l[threadIdx.x] = Wg[threadIdx.x];
    if (threadIdx.x < 9)  bg_l[threadIdx.x] = bg[threadIdx.x];
    __syncthreads();
    for (int idx = threadIdx.x; idx < C_; idx += 128) {
        float s0 = 0.f;
#pragma unroll
        for (int p = 0; p < 9; ++p) s0 += px_l[idx * 9 + p];
        emb_l[idx] = s0 * (1.f / 9.f);
    }
    __syncthreads();

    float accq[9];
#pragma unroll
    for (int p = 0; p < 9; ++p) accq[p] = bq[o];
    float acck = bk[o];
    const float* wq_row = Wq + (size_t)o * C_;
    const float* wk_row = Wk + (size_t)o * C_;
    for (int i = 0; i < C_; ++i) {
        const float w = wq_row[i];
#pragma unroll
        for (int p = 0; p < 9; ++p) accq[p] = fmaf(w, px_l[i * 9 + p], accq[p]);
        acck = fmaf(wk_row[i], emb_l[i], acck);
    }

    float kf[9], mean = 0.f;
#pragma unroll
    for (int q = 0; q < 9; ++q) {
        float a = bg_l[q];
#pragma unroll
        for (int p = 0; p < 9; ++p) a = fmaf(accq[p], wg_l[q * 9 + p], a);
        kf[q] = a; mean += a;
    }
    mean *= (1.f / 9.f);
    const float sig = 1.f / (1.f + expf(-acck));
#pragma unroll
    for (int q = 0; q < 9; ++q)
        kernT[((size_t)b * 9 + q) * C_ + o] = f2bf(kf[q] - sig * mean);
}

// ---------------------------------------------------------------------------
// bf16 MFMA GEMM (R4-exact): BK=64, XOR-swizzled LDS, XCD-chunked 1-D grid.
// ---------------------------------------------------------------------------
template<int BIAS_COL, bool OUT_BF16, int BMAJOR>
__global__ __launch_bounds__(256) void gemm_bt(const unsigned short* __restrict__ A,
                                               const unsigned short* __restrict__ Bt,
                                               const float* __restrict__ bias,
                                               void* __restrict__ Yv,
                                               int N, int nMt, int nNt, int perB,
                                               long long sA, long long sB, long long sY) {
    const int q8  = gridDim.x >> 3;
    const int swz = (blockIdx.x & 7) * q8 + (blockIdx.x >> 3);
    const int b   = swz / perB;
    const int r   = swz % perB;
    const int mtile = BMAJOR ? (r % nMt) : (r / nNt);
    const int ntile = BMAJOR ? (r / nMt) : (r % nNt);
    const int m0 = mtile * 128, n0 = ntile * 128;

    const int t = threadIdx.x;
    const int l = t & 63, w = t >> 6;
    const unsigned short* Ab = A + (size_t)b * sA;
    const unsigned short* Bb = Bt + (size_t)b * sB;

    __shared__ __align__(16) unsigned short As[128 * 64];
    __shared__ __align__(16) unsigned short Bs[128 * 64];

    f32x4 acc[4][4] = {};
    const int wm = w >> 1, wn = w & 1;

    const int srow = t >> 3;
    const int skc  = t & 7;
    const int gkc  = skc ^ (srow & 7);

    const int lr = l & 15;
    const int kq = l >> 4;
    const int xorv = lr & 7;

    for (int k0 = 0; k0 < 384; k0 += 64) {
#pragma unroll
        for (int j = 0; j < 4; ++j)
            __builtin_amdgcn_global_load_lds(
                (gbl_void*)(Ab + (size_t)(m0 + 32 * j + srow) * 384 + k0 + gkc * 8),
                (lds_void*)(As + (32 * j + srow) * 64 + skc * 8), 16, 0, 0);
#pragma unroll
        for (int j = 0; j < 4; ++j)
            __builtin_amdgcn_global_load_lds(
                (gbl_void*)(Bb + (size_t)(n0 + 32 * j + srow) * 384 + k0 + gkc * 8),
                (lds_void*)(Bs + (32 * j + srow) * 64 + skc * 8), 16, 0, 0);
        __syncthreads();

#pragma unroll
        for (int sub = 0; sub < 2; ++sub) {
            const int kc = sub * 4 + kq;
            const int ko = (kc ^ xorv) * 8;
            bf16x8 af[4], bfr[4];
#pragma unroll
            for (int f = 0; f < 4; ++f)
                af[f] = *reinterpret_cast<const bf16x8*>(&As[(wm * 64 + f * 16 + lr) * 64 + ko]);
#pragma unroll
            for (int f = 0; f < 4; ++f)
                bfr[f] = *reinterpret_cast<const bf16x8*>(&Bs[(wn * 64 + f * 16 + lr) * 64 + ko]);
#pragma unroll
            for (int fm = 0; fm < 4; ++fm)
#pragma unroll
                for (int fn = 0; fn < 4; ++fn)
                    acc[fm][fn] = __builtin_amdgcn_mfma_f32_16x16x32_bf16(af[fm], bfr[fn], acc[fm][fn], 0, 0, 0);
        }
        __syncthreads();
    }

    const int lg = (l >> 4) * 4;
#pragma unroll
    for (int fm = 0; fm < 4; ++fm) {
        const int row = m0 + wm * 64 + fm * 16 + lg;
#pragma unroll
        for (int fn = 0; fn < 4; ++fn) {
            const int col = n0 + wn * 64 + fn * 16 + lr;
            const float cb = BIAS_COL ? bias[col] : 0.f;
#pragma unroll
            for (int rr = 0; rr < 4; ++rr) {
                const float v = acc[fm][fn][rr] + (BIAS_COL ? cb : bias[row + rr]);
                if (OUT_BF16)
                    ((unsigned short*)Yv)[(size_t)b * sY + (size_t)(row + rr) * N + col] = f2bf(v);
                else
                    ((float*)Yv)[(size_t)b * sY + (size_t)(row + rr) * N + col] = v;
            }
        }
    }
}

// ---------------------------------------------------------------------------
// dwT v2: depthwise dynamic 3x3 (channel-last), one thread = 4 consecutive
// same-row pixels x 8 channels.  3x6 neighbor patch preloaded (18 loads for
// 4 outputs, vs 36), kv reused.  OOB taps = zero vector -> fmaf(0,k,acc)=acc,
// bit-identical to the skip version.  grid (108, 16).
// ---------------------------------------------------------------------------
__global__ __launch_bounds__(256) void dwT_kernel(const unsigned short* __restrict__ vT,
                                                  const unsigned short* __restrict__ kT,
                                                  unsigned short* __restrict__ oT) {
    const int b = blockIdx.y;
    const int u = blockIdx.x * 256 + threadIdx.x;   // 27648 units
    const int cg = u % 48;
    const int pg = u / 48;          // 0..575
    const int p0 = pg * 4;          // 4 consecutive pixels, same row (48%4==0)
    const int h  = p0 / W_;
    const int w0 = p0 % W_;
    const int c0 = cg * 8;
    const size_t base = (size_t)b * HW_ * C_;

    u16x8 kv[9];
#pragma unroll
    for (int q = 0; q < 9; ++q)
        kv[q] = *(const u16x8*)&kT[((size_t)b * 9 + q) * C_ + c0];

    const u16x8 zero = {};
    u16x8 v[3][6];
#pragma unroll
    for (int di = 0; di < 3; ++di) {
        const int hh = h + di - 1;
        const bool hok = (hh >= 0) && (hh < H_);
#pragma unroll
        for (int c = 0; c < 6; ++c) {
            const int wn = w0 + c - 1;
            const bool ok = hok && (wn >= 0) && (wn < W_);
            v[di][c] = ok ? *(const u16x8*)&vT[base + (size_t)(hh * W_ + wn) * C_ + c0]
                          : zero;
        }
    }

#pragma unroll
    for (int j = 0; j < 4; ++j) {
        float acc[8] = {};
#pragma unroll
        for (int di = 0; di < 3; ++di)
#pragma unroll
            for (int dj = 0; dj < 3; ++dj) {
                const int q = di * 3 + dj;
                const u16x8 vv = v[di][j + dj];
#pragma unroll
                for (int e = 0; e < 8; ++e)
                    acc[e] = fmaf(bf2f(vv[e]), bf2f(kv[q][e]), acc[e]);
            }
        u16x8 o;
#pragma unroll
        for (int e = 0; e < 8; ++e) o[e] = f2bf(acc[e]);
        *(u16x8*)&oT[base + (size_t)(p0 + j) * C_ + c0] = o;
    }
}

// ---------------------------------------------------------------------------
extern "C" void kernel_launch(void* const* d_in, const int* in_sizes, int n_in,
                              void* d_out, int out_size, void* d_ws, size_t ws_size,
                              hipStream_t stream) {
    const float* x  = (const float*)d_in[0];
    const float* Wq = (const float*)d_in[1];
    const float* bq = (const float*)d_in[2];
    const float* Wk = (const float*)d_in[3];
    const float* bk = (const float*)d_in[4];
    const float* Wv = (const float*)d_in[5];
    const float* bv = (const float*)d_in[6];
    const float* Wg = (const float*)d_in[7];
    const float* bg = (const float*)d_in[8];
    const float* Wp = (const float*)d_in[9];
    const float* bp = (const float*)d_in[10];
    float* out = (float*)d_out;

    char* ws = (char*)d_ws;
    const size_t bhwc2 = (size_t)B_ * HW_ * C_ * 2;          // 28,311,552 B
    unsigned short* xT     = (unsigned short*)ws;             // reused as out2T
    unsigned short* valueT = (unsigned short*)(ws + bhwc2);
    unsigned short* Wvb    = (unsigned short*)(ws + 2 * bhwc2);
    unsigned short* Wpb    = (unsigned short*)(ws + 2 * bhwc2 + 294912);
    float*          px     = (float*)(ws + 2 * bhwc2 + 2 * 294912);
    unsigned short* kernT  = (unsigned short*)(ws + 2 * bhwc2 + 2 * 294912 + 221184);
    unsigned short* out2T  = xT;   // xT dead after GEMM1

    // 1. tcast + weight-cast in one launch
    tcastw_kernel<<<3744, 256, 0, stream>>>(x, Wv, Wp, Wvb, Wpb, xT);
    // 2. pool from xT (bf16)
    poolT_kernel<<<dim3(9, C_ / 64, B_), 256, 0, stream>>>(xT, px);
    // 3. dynamic kernels
    small_kernel<<<dim3(3, B_), 128, 0, stream>>>(px, Wq, bq, Wk, bk, Wg, bg, kernT);
    // 4. GEMM1: valueT[(b.p)][c] = xT[(b.p)][:] . Wv[c][:] + bv[c]
    gemm_bt<1, true, 0><<<864, 256, 0, stream>>>(
        xT, Wvb, bv, (void*)valueT, C_, 288, 3, 864, 0LL, 0LL, 0LL);
    // 5. depthwise dynamic 3x3 (4 pixels/thread)
    dwT_kernel<<<dim3(108, B_), 256, 0, stream>>>(valueT, kernT, out2T);
    // 6. GEMM2: out[b][c][p] = Wp[c][:] . out2T[b][p][:] + bp[c]
    gemm_bt<0, false, 1><<<864, 256, 0, stream>>>(
        Wpb, out2T, bp, (void*)out, HW_, 3, 18, 54,
        0LL, (long long)HW_ * C_, (long long)C_ * HW_);
}

// Round 11
// 112.603 us; speedup vs baseline: 1.4120x; 1.0331x over previous
//
#include <hip/hip_runtime.h>
#include <cstdint>
#include <cstddef>

// Problem constants
#define B_  16
#define C_  384
#define H_  48
#define W_  48
#define HW_ 2304        // 48*48

typedef __bf16 bf16x8 __attribute__((ext_vector_type(8)));
typedef float  f32x4  __attribute__((ext_vector_type(4)));
typedef unsigned short u16x8 __attribute__((ext_vector_type(8)));

typedef __attribute__((address_space(3))) void       lds_void;
typedef const __attribute__((address_space(1))) void gbl_void;

__device__ __forceinline__ unsigned short f2bf(float f) {
    union { float f; unsigned int u; } v; v.f = f;
    unsigned int r = v.u + 0x7fffu + ((v.u >> 16) & 1u);   // RNE
    return (unsigned short)(r >> 16);
}
__device__ __forceinline__ float bf2f(unsigned short u) {
    union { unsigned int u; float f; } v; v.u = ((unsigned int)u) << 16;
    return v.f;
}

// ---------------------------------------------------------------------------
// tcastw (R10-exact): tcast + weight-cast in ONE launch, partitioned by block.
// ---------------------------------------------------------------------------
__global__ __launch_bounds__(256) void tcastw_kernel(const float* __restrict__ x,
                                                     const float* __restrict__ Wv,
                                                     const float* __restrict__ Wp,
                                                     unsigned short* __restrict__ Wvb,
                                                     unsigned short* __restrict__ Wpb,
                                                     unsigned short* __restrict__ xT) {
    __shared__ unsigned short tile[64][68];
    const int blk = blockIdx.x;
    const int t   = threadIdx.x;

    if (blk < 3456) {
        const int b    = blk / 216;
        const int r216 = blk % 216;
        const int c0   = (r216 / 36) * 64;
        const int p0   = (r216 % 36) * 64;
        const float* xb = x + ((size_t)b * C_ + c0) * HW_ + p0;

#pragma unroll
        for (int pass = 0; pass < 4; ++pass) {
            const int cr = pass * 16 + (t >> 4);
            const int pc = (t & 15) * 4;
            const float4 v = *(const float4*)&xb[(size_t)cr * HW_ + pc];
            tile[pc + 0][cr] = f2bf(v.x); tile[pc + 1][cr] = f2bf(v.y);
            tile[pc + 2][cr] = f2bf(v.z); tile[pc + 3][cr] = f2bf(v.w);
        }
        __syncthreads();
        unsigned short* xTb = xT + ((size_t)b * HW_ + p0) * C_ + c0;
#pragma unroll
        for (int pass = 0; pass < 4; ++pass) {
            const int pr = pass * 16 + (t >> 4);
            const int cc = (t & 15) * 4;
            *(ushort4*)&xTb[(size_t)pr * C_ + cc] = *(const ushort4*)&tile[pr][cc];
        }
    } else {
        const int cblk = blk - 3456;
        const float* s = (cblk < 144) ? Wv : Wp;
        unsigned short* d = (cblk < 144) ? Wvb : Wpb;
        const int i = ((cblk < 144 ? cblk : cblk - 144) * 256 + t) * 4;
        const float4 v = *(const float4*)&s[i];
        ushort4 o; o.x = f2bf(v.x); o.y = f2bf(v.y); o.z = f2bf(v.z); o.w = f2bf(v.w);
        *(ushort4*)&d[i] = o;
    }
}

// ---------------------------------------------------------------------------
// FUSED launch: blocks [0,864) = GEMM1 (R4/R10-exact gemm_bt<1,true,0> body,
// XCD swizzle over the 864 gemm blocks, q8=108 hardcoded);
// blocks [864,1728) = poolT (R10-exact body, LDS overlaid on As).
// Both consume xT only; outputs (valueT, px) disjoint -> race-free.
// ---------------------------------------------------------------------------
__global__ __launch_bounds__(256) void gemm1_pool_kernel(const unsigned short* __restrict__ xT,
                                                         const unsigned short* __restrict__ Wvb,
                                                         const float* __restrict__ bv,
                                                         unsigned short* __restrict__ valueT,
                                                         float* __restrict__ px) {
    __shared__ __align__(16) unsigned short As[128 * 64];   // 16 KB (pool overlays 1 KB)
    __shared__ __align__(16) unsigned short Bs[128 * 64];   // 16 KB
    const int t = threadIdx.x;

    if (blockIdx.x < 864) {
        // ---------------- GEMM1 ----------------
        const int swz = (blockIdx.x & 7) * 108 + (blockIdx.x >> 3);   // bijective, 864%8==0
        const int mtile = swz / 3;
        const int ntile = swz % 3;
        const int m0 = mtile * 128, n0 = ntile * 128;

        const int l = t & 63, w = t >> 6;
        f32x4 acc[4][4] = {};
        const int wm = w >> 1, wn = w & 1;

        const int srow = t >> 3;
        const int skc  = t & 7;
        const int gkc  = skc ^ (srow & 7);

        const int lr = l & 15;
        const int kq = l >> 4;
        const int xorv = lr & 7;

        for (int k0 = 0; k0 < 384; k0 += 64) {
#pragma unroll
            for (int j = 0; j < 4; ++j)
                __builtin_amdgcn_global_load_lds(
                    (gbl_void*)(xT + (size_t)(m0 + 32 * j + srow) * 384 + k0 + gkc * 8),
                    (lds_void*)(As + (32 * j + srow) * 64 + skc * 8), 16, 0, 0);
#pragma unroll
            for (int j = 0; j < 4; ++j)
                __builtin_amdgcn_global_load_lds(
                    (gbl_void*)(Wvb + (size_t)(n0 + 32 * j + srow) * 384 + k0 + gkc * 8),
                    (lds_void*)(Bs + (32 * j + srow) * 64 + skc * 8), 16, 0, 0);
            __syncthreads();

#pragma unroll
            for (int sub = 0; sub < 2; ++sub) {
                const int kc = sub * 4 + kq;
                const int ko = (kc ^ xorv) * 8;
                bf16x8 af[4], bfr[4];
#pragma unroll
                for (int f = 0; f < 4; ++f)
                    af[f] = *reinterpret_cast<const bf16x8*>(&As[(wm * 64 + f * 16 + lr) * 64 + ko]);
#pragma unroll
                for (int f = 0; f < 4; ++f)
                    bfr[f] = *reinterpret_cast<const bf16x8*>(&Bs[(wn * 64 + f * 16 + lr) * 64 + ko]);
#pragma unroll
                for (int fm = 0; fm < 4; ++fm)
#pragma unroll
                    for (int fn = 0; fn < 4; ++fn)
                        acc[fm][fn] = __builtin_amdgcn_mfma_f32_16x16x32_bf16(af[fm], bfr[fn], acc[fm][fn], 0, 0, 0);
            }
            __syncthreads();
        }

        const int lg = (l >> 4) * 4;
#pragma unroll
        for (int fm = 0; fm < 4; ++fm) {
            const int row = m0 + wm * 64 + fm * 16 + lg;
#pragma unroll
            for (int fn = 0; fn < 4; ++fn) {
                const int col = n0 + wn * 64 + fn * 16 + lr;
                const float cb = bv[col];
#pragma unroll
                for (int rr = 0; rr < 4; ++rr)
                    valueT[(size_t)(row + rr) * C_ + col] = f2bf(acc[fm][fn][rr] + cb);
            }
        }
    } else {
        // ---------------- poolT (R10-exact body) ----------------
        const int pb = blockIdx.x - 864;
        const int r  = pb % 9;
        const int c0 = ((pb / 9) % 6) * 64;
        const int b  = pb / 54;
        const int wv = t >> 6;
        const int l  = t & 63;
        const int i  = l >> 3;
        const int cg = l & 7;
        const int ri = r / 3, rj = r % 3;
        const int cbase = c0 + cg * 8;

        float* s = (float*)As;           // overlay: [4][64] floats = 1 KB

        float acc[8] = {};
#pragma unroll
        for (int k = 0; k < 8; ++k) {
            const int pix = wv * 64 + i + k * 8;
            const int h = ri * 16 + (pix >> 4), w2 = rj * 16 + (pix & 15);
            const u16x8 v = *(const u16x8*)&xT[((size_t)b * HW_ + h * W_ + w2) * C_ + cbase];
#pragma unroll
            for (int e = 0; e < 8; ++e) acc[e] += bf2f(v[e]);
        }
#pragma unroll
        for (int m = 8; m <= 32; m <<= 1)
#pragma unroll
            for (int e = 0; e < 8; ++e) acc[e] += __shfl_xor(acc[e], m, 64);
        if (i == 0)
#pragma unroll
            for (int e = 0; e < 8; ++e) s[wv * 64 + cg * 8 + e] = acc[e];
        __syncthreads();
        if (t < 64) {
            const float tot = s[0 * 64 + t] + s[1 * 64 + t] + s[2 * 64 + t] + s[3 * 64 + t];
            px[((size_t)b * C_ + c0 + t) * 9 + r] = tot * (1.f / 256.f);
        }
    }
}

// ---------------------------------------------------------------------------
// small projections -> kernT[b][q][c] bf16 (R10-exact).
// ---------------------------------------------------------------------------
__global__ void small_kernel(const float* __restrict__ px,
                             const float* __restrict__ Wq, const float* __restrict__ bq,
                             const float* __restrict__ Wk, const float* __restrict__ bk,
                             const float* __restrict__ Wg, const float* __restrict__ bg,
                             unsigned short* __restrict__ kernT) {
    const int b = blockIdx.y;
    const int o = blockIdx.x * 128 + threadIdx.x;

    __shared__ float px_l[C_ * 9];
    __shared__ float emb_l[C_];
    __shared__ float wg_l[81];
    __shared__ float bg_l[9];

    for (int idx = threadIdx.x; idx < C_ * 9; idx += 128) px_l[idx] = px[(size_t)b * C_ * 9 + idx];
    if (threadIdx.x < 81) wg_l[threadIdx.x] = Wg[threadIdx.x];
    if (threadIdx.x < 9)  bg_l[threadIdx.x] = bg[threadIdx.x];
    __syncthreads();
    for (int idx = threadIdx.x; idx < C_; idx += 128) {
        float s0 = 0.f;
#pragma unroll
        for (int p = 0; p < 9; ++p) s0 += px_l[idx * 9 + p];
        emb_l[idx] = s0 * (1.f / 9.f);
    }
    __syncthreads();

    float accq[9];
#pragma unroll
    for (int p = 0; p < 9; ++p) accq[p] = bq[o];
    float acck = bk[o];
    const float* wq_row = Wq + (size_t)o * C_;
    const float* wk_row = Wk + (size_t)o * C_;
    for (int i = 0; i < C_; ++i) {
        const float w = wq_row[i];
#pragma unroll
        for (int p = 0; p < 9; ++p) accq[p] = fmaf(w, px_l[i * 9 + p], accq[p]);
        acck = fmaf(wk_row[i], emb_l[i], acck);
    }

    float kf[9], mean = 0.f;
#pragma unroll
    for (int q = 0; q < 9; ++q) {
        float a = bg_l[q];
#pragma unroll
        for (int p = 0; p < 9; ++p) a = fmaf(accq[p], wg_l[q * 9 + p], a);
        kf[q] = a; mean += a;
    }
    mean *= (1.f / 9.f);
    const float sig = 1.f / (1.f + expf(-acck));
#pragma unroll
    for (int q = 0; q < 9; ++q)
        kernT[((size_t)b * 9 + q) * C_ + o] = f2bf(kf[q] - sig * mean);
}

// ---------------------------------------------------------------------------
// bf16 MFMA GEMM (R4-exact) — used for GEMM2.
// ---------------------------------------------------------------------------
template<int BIAS_COL, bool OUT_BF16, int BMAJOR>
__global__ __launch_bounds__(256) void gemm_bt(const unsigned short* __restrict__ A,
                                               const unsigned short* __restrict__ Bt,
                                               const float* __restrict__ bias,
                                               void* __restrict__ Yv,
                                               int N, int nMt, int nNt, int perB,
                                               long long sA, long long sB, long long sY) {
    const int q8  = gridDim.x >> 3;
    const int swz = (blockIdx.x & 7) * q8 + (blockIdx.x >> 3);
    const int b   = swz / perB;
    const int r   = swz % perB;
    const int mtile = BMAJOR ? (r % nMt) : (r / nNt);
    const int ntile = BMAJOR ? (r / nMt) : (r % nNt);
    const int m0 = mtile * 128, n0 = ntile * 128;

    const int t = threadIdx.x;
    const int l = t & 63, w = t >> 6;
    const unsigned short* Ab = A + (size_t)b * sA;
    const unsigned short* Bb = Bt + (size_t)b * sB;

    __shared__ __align__(16) unsigned short As[128 * 64];
    __shared__ __align__(16) unsigned short Bs[128 * 64];

    f32x4 acc[4][4] = {};
    const int wm = w >> 1, wn = w & 1;

    const int srow = t >> 3;
    const int skc  = t & 7;
    const int gkc  = skc ^ (srow & 7);

    const int lr = l & 15;
    const int kq = l >> 4;
    const int xorv = lr & 7;

    for (int k0 = 0; k0 < 384; k0 += 64) {
#pragma unroll
        for (int j = 0; j < 4; ++j)
            __builtin_amdgcn_global_load_lds(
                (gbl_void*)(Ab + (size_t)(m0 + 32 * j + srow) * 384 + k0 + gkc * 8),
                (lds_void*)(As + (32 * j + srow) * 64 + skc * 8), 16, 0, 0);
#pragma unroll
        for (int j = 0; j < 4; ++j)
            __builtin_amdgcn_global_load_lds(
                (gbl_void*)(Bb + (size_t)(n0 + 32 * j + srow) * 384 + k0 + gkc * 8),
                (lds_void*)(Bs + (32 * j + srow) * 64 + skc * 8), 16, 0, 0);
        __syncthreads();

#pragma unroll
        for (int sub = 0; sub < 2; ++sub) {
            const int kc = sub * 4 + kq;
            const int ko = (kc ^ xorv) * 8;
            bf16x8 af[4], bfr[4];
#pragma unroll
            for (int f = 0; f < 4; ++f)
                af[f] = *reinterpret_cast<const bf16x8*>(&As[(wm * 64 + f * 16 + lr) * 64 + ko]);
#pragma unroll
            for (int f = 0; f < 4; ++f)
                bfr[f] = *reinterpret_cast<const bf16x8*>(&Bs[(wn * 64 + f * 16 + lr) * 64 + ko]);
#pragma unroll
            for (int fm = 0; fm < 4; ++fm)
#pragma unroll
                for (int fn = 0; fn < 4; ++fn)
                    acc[fm][fn] = __builtin_amdgcn_mfma_f32_16x16x32_bf16(af[fm], bfr[fn], acc[fm][fn], 0, 0, 0);
        }
        __syncthreads();
    }

    const int lg = (l >> 4) * 4;
#pragma unroll
    for (int fm = 0; fm < 4; ++fm) {
        const int row = m0 + wm * 64 + fm * 16 + lg;
#pragma unroll
        for (int fn = 0; fn < 4; ++fn) {
            const int col = n0 + wn * 64 + fn * 16 + lr;
            const float cb = BIAS_COL ? bias[col] : 0.f;
#pragma unroll
            for (int rr = 0; rr < 4; ++rr) {
                const float v = acc[fm][fn][rr] + (BIAS_COL ? cb : bias[row + rr]);
                if (OUT_BF16)
                    ((unsigned short*)Yv)[(size_t)b * sY + (size_t)(row + rr) * N + col] = f2bf(v);
                else
                    ((float*)Yv)[(size_t)b * sY + (size_t)(row + rr) * N + col] = v;
            }
        }
    }
}

// ---------------------------------------------------------------------------
// dwT v2 (R10-exact): 4 consecutive same-row pixels x 8 channels per thread.
// ---------------------------------------------------------------------------
__global__ __launch_bounds__(256) void dwT_kernel(const unsigned short* __restrict__ vT,
                                                  const unsigned short* __restrict__ kT,
                                                  unsigned short* __restrict__ oT) {
    const int b = blockIdx.y;
    const int u = blockIdx.x * 256 + threadIdx.x;
    const int cg = u % 48;
    const int pg = u / 48;
    const int p0 = pg * 4;
    const int h  = p0 / W_;
    const int w0 = p0 % W_;
    const int c0 = cg * 8;
    const size_t base = (size_t)b * HW_ * C_;

    u16x8 kv[9];
#pragma unroll
    for (int q = 0; q < 9; ++q)
        kv[q] = *(const u16x8*)&kT[((size_t)b * 9 + q) * C_ + c0];

    const u16x8 zero = {};
    u16x8 v[3][6];
#pragma unroll
    for (int di = 0; di < 3; ++di) {
        const int hh = h + di - 1;
        const bool hok = (hh >= 0) && (hh < H_);
#pragma unroll
        for (int c = 0; c < 6; ++c) {
            const int wn = w0 + c - 1;
            const bool ok = hok && (wn >= 0) && (wn < W_);
            v[di][c] = ok ? *(const u16x8*)&vT[base + (size_t)(hh * W_ + wn) * C_ + c0]
                          : zero;
        }
    }

#pragma unroll
    for (int j = 0; j < 4; ++j) {
        float acc[8] = {};
#pragma unroll
        for (int di = 0; di < 3; ++di)
#pragma unroll
            for (int dj = 0; dj < 3; ++dj) {
                const int q = di * 3 + dj;
                const u16x8 vv = v[di][j + dj];
#pragma unroll
                for (int e = 0; e < 8; ++e)
                    acc[e] = fmaf(bf2f(vv[e]), bf2f(kv[q][e]), acc[e]);
            }
        u16x8 o;
#pragma unroll
        for (int e = 0; e < 8; ++e) o[e] = f2bf(acc[e]);
        *(u16x8*)&oT[base + (size_t)(p0 + j) * C_ + c0] = o;
    }
}

// ---------------------------------------------------------------------------
extern "C" void kernel_launch(void* const* d_in, const int* in_sizes, int n_in,
                              void* d_out, int out_size, void* d_ws, size_t ws_size,
                              hipStream_t stream) {
    const float* x  = (const float*)d_in[0];
    const float* Wq = (const float*)d_in[1];
    const float* bq = (const float*)d_in[2];
    const float* Wk = (const float*)d_in[3];
    const float* bk = (const float*)d_in[4];
    const float* Wv = (const float*)d_in[5];
    const float* bv = (const float*)d_in[6];
    const float* Wg = (const float*)d_in[7];
    const float* bg = (const float*)d_in[8];
    const float* Wp = (const float*)d_in[9];
    const float* bp = (const float*)d_in[10];
    float* out = (float*)d_out;

    char* ws = (char*)d_ws;
    const size_t bhwc2 = (size_t)B_ * HW_ * C_ * 2;          // 28,311,552 B
    unsigned short* xT     = (unsigned short*)ws;             // reused as out2T
    unsigned short* valueT = (unsigned short*)(ws + bhwc2);
    unsigned short* Wvb    = (unsigned short*)(ws + 2 * bhwc2);
    unsigned short* Wpb    = (unsigned short*)(ws + 2 * bhwc2 + 294912);
    float*          px     = (float*)(ws + 2 * bhwc2 + 2 * 294912);
    unsigned short* kernT  = (unsigned short*)(ws + 2 * bhwc2 + 2 * 294912 + 221184);
    unsigned short* out2T  = xT;   // xT dead after GEMM1

    // 1. tcast + weight-cast
    tcastw_kernel<<<3744, 256, 0, stream>>>(x, Wv, Wp, Wvb, Wpb, xT);
    // 2. GEMM1 (blocks 0-863) + poolT (blocks 864-1727) in one launch
    gemm1_pool_kernel<<<1728, 256, 0, stream>>>(xT, Wvb, bv, valueT, px);
    // 3. dynamic kernels
    small_kernel<<<dim3(3, B_), 128, 0, stream>>>(px, Wq, bq, Wk, bk, Wg, bg, kernT);
    // 4. depthwise dynamic 3x3
    dwT_kernel<<<dim3(108, B_), 256, 0, stream>>>(valueT, kernT, out2T);
    // 5. GEMM2: out[b][c][p] = Wp[c][:] . out2T[b][p][:] + bp[c]
    gemm_bt<0, false, 1><<<864, 256, 0, stream>>>(
        Wpb, out2T, bp, (void*)out, HW_, 3, 18, 54,
        0LL, (long long)HW_ * C_, (long long)C_ * HW_);
}